// Round 11
// baseline (133.317 us; speedup 1.0000x reference)
//
#include <hip/hip_runtime.h>
#include <hip/hip_fp8.h>

// B=256, F=32, N=16, D=512
//   sims[b,f,c,n] = relu(face[b,f]·ner[c,n])      (8192 x 4096 NT GEMM, K=512)
//   S_all[b,f]    = sum_{c,n} masked(sims)        (masked: ==1.0 -> 0)
//   pos[b,f]      = sum_n sims[b,f,b,n]           (unmasked diagonal)
//   diag_m[b,f]   = sum_n masked(sims[b,f,b,n])
//   loss = sum(relu((S_all-diag_m)/255 - pos + 0.2) * face_mask) / 256
//
// Round 11: MX-fp8 GEMM (e4m3, scales fixed to 1.0) via
// mfma_scale_f32_16x16x128_f8f6f4 -- 2x bf16 MFMA rate, half the staging and
// LDS bytes, in the r2-proven 128x128 / 4-wave / 2-barrier loop (4 K-tiles of
// 128). pos/diag_m/mask computed in fp32 by a fast standalone diag kernel
// (lane-parallel over n), so fp8 error only enters through S_all/255.

#define DIM_D 512
#define M_TOT 8192
#define N_TOT 4096

typedef __attribute__((ext_vector_type(4))) int   i32x4;
typedef __attribute__((ext_vector_type(8))) int   i32x8;
typedef __attribute__((ext_vector_type(4))) float f32x4;

__device__ __forceinline__ unsigned char f2e4m3(float f) {
  __hip_fp8_e4m3 t(f);
  return (unsigned char)t.__x;
}

// ---------------------------------------------------------------------------
// cvt: face+ner fp32 -> e4m3 bytes, plus face_mask. One wave per 512-row.
// ---------------------------------------------------------------------------
__global__ __launch_bounds__(256) void cvt_fp8(
    const float* __restrict__ face, const float* __restrict__ ner,
    unsigned char* __restrict__ face8, unsigned char* __restrict__ ner8,
    float* __restrict__ mask) {
  const int gw = blockIdx.x * 4 + (threadIdx.x >> 6);
  const int lane = threadIdx.x & 63;
  const bool isFace = gw < M_TOT;
  const int row = isFace ? gw : gw - M_TOT;
  const float* src = (isFace ? face : ner) + (size_t)row * DIM_D;
  unsigned char* dst = (isFace ? face8 : ner8) + (size_t)row * DIM_D;

  const float4 f0 = ((const float4*)src)[lane * 2];
  const float4 f1 = ((const float4*)src)[lane * 2 + 1];
  unsigned long long pk = 0;
  pk |= (unsigned long long)f2e4m3(f0.x) << 0;
  pk |= (unsigned long long)f2e4m3(f0.y) << 8;
  pk |= (unsigned long long)f2e4m3(f0.z) << 16;
  pk |= (unsigned long long)f2e4m3(f0.w) << 24;
  pk |= (unsigned long long)f2e4m3(f1.x) << 32;
  pk |= (unsigned long long)f2e4m3(f1.y) << 40;
  pk |= (unsigned long long)f2e4m3(f1.z) << 48;
  pk |= (unsigned long long)f2e4m3(f1.w) << 56;
  *(unsigned long long*)(dst + lane * 8) = pk;

  if (isFace) {
    float fs = f0.x + f0.y + f0.z + f0.w + f1.x + f1.y + f1.z + f1.w;
#pragma unroll
    for (int off = 1; off < 64; off <<= 1) fs += __shfl_xor(fs, off);
    if (lane == 0) mask[row] = (fs != 0.0f) ? 1.0f : 0.0f;
  }
}

// ---------------------------------------------------------------------------
// Fast fp32 diagonal: pos/diag_m per (b,f) row. One wave per row; 4 lanes
// per n (n = lane>>2), each lane dots a contiguous 128-elem chunk (float4).
// Quad-reduce -> relu/mask -> full-wave tree (x4 overcount -> *0.25).
// ---------------------------------------------------------------------------
__global__ __launch_bounds__(256) void grl_diag(
    const float* __restrict__ face, const float* __restrict__ ner,
    float* __restrict__ pos, float* __restrict__ diagm) {
  const int lane = threadIdx.x & 63;
  const int row = blockIdx.x * 4 + (threadIdx.x >> 6);
  const int b = row >> 5;
  const int nn = lane >> 2;   // n handled by this lane
  const int q = lane & 3;     // chunk
  const float* fp = face + (size_t)row * DIM_D + q * 128;
  const float* np_ = ner + ((size_t)b * 16 + nn) * DIM_D + q * 128;

  float p = 0.0f;
#pragma unroll
  for (int j = 0; j < 32; ++j) {
    const float4 fv = ((const float4*)fp)[j];
    const float4 nv = ((const float4*)np_)[j];
    p = fmaf(fv.x, nv.x, p);
    p = fmaf(fv.y, nv.y, p);
    p = fmaf(fv.z, nv.z, p);
    p = fmaf(fv.w, nv.w, p);
  }
  p += __shfl_xor(p, 1);
  p += __shfl_xor(p, 2);           // all 4 lanes of quad hold dot(n)
  float v = p > 0.0f ? p : 0.0f;
  float ps = v;
  float ds = (v == 1.0f) ? 0.0f : v;
#pragma unroll
  for (int off = 1; off < 64; off <<= 1) {
    ps += __shfl_xor(ps, off);
    ds += __shfl_xor(ds, off);
  }
  if (lane == 0) {
    pos[row] = ps * 0.25f;   // each n counted 4x
    diagm[row] = ds * 0.25f;
  }
}

// ---------------------------------------------------------------------------
// MX-fp8 GEMM: 128x128 tile, 4 waves (2x2), wave-tile 64x64 = 4x4 frags of
// 16x16, K = 4 tiles of 128. LDS 32 KB static (A 16K + B 16K), single buffer,
// r2-style 2-barrier loop. Row = 128 B = 8 x 16B slots; slot s of row r
// stored at position s ^ (r&7) (2-way bank alias = free); staged with
// pre-swizzled global source + linear LDS dst (rule #21).
// Scales fixed at E8M0 127 (= 1.0) -> plain fp8 matmul at 2x bf16 rate.
// ---------------------------------------------------------------------------
#define GLDS(SRC, DSTOFF)                                                     \
  __builtin_amdgcn_global_load_lds(                                           \
      (const __attribute__((address_space(1))) void*)(SRC),                   \
      (__attribute__((address_space(3))) void*)(lds + (DSTOFF)), 16, 0, 0)

__global__ __launch_bounds__(256) void grl_gemm_fp8(
    const unsigned char* __restrict__ A8, const unsigned char* __restrict__ B8,
    float* __restrict__ S_all) {
  __shared__ __align__(16) unsigned char lds[32768];  // A [0,16K), B [16K,32K)

  const int tid = threadIdx.x;
  const int lane = tid & 63;
  const int wid = tid >> 6;
  const int wr = wid >> 1;   // 0..1 (M)
  const int wc = wid & 1;    // 0..1 (N)
  const int m0 = blockIdx.x * 128;
  const int n0 = blockIdx.y * 128;

  // ---- stager: 4 GLDS per matrix per K-tile; instr i covers 32 rows -----
  // lane -> row = i*32 + wid*8 + (lane>>3), pos = lane&7;
  // source slot = pos ^ (row&7) = (lane&7) ^ (lane>>3)
  const int sg = ((lane & 7) ^ (lane >> 3)) * 16;
  const int srow = wid * 8 + (lane >> 3);
  const unsigned char* gA = A8 + (size_t)(m0 + srow) * DIM_D + sg;
  const unsigned char* gB = B8 + (size_t)(n0 + srow) * DIM_D + sg;
  const int ldst = wid * 1024;

#define STAGE(T)                                                        \
  do {                                                                  \
    _Pragma("unroll") for (int i_ = 0; i_ < 4; ++i_) {                  \
      GLDS(gA + (T) * 128 + (size_t)i_ * 32 * DIM_D, i_ * 4096 + ldst); \
      GLDS(gB + (T) * 128 + (size_t)i_ * 32 * DIM_D,                    \
           16384 + i_ * 4096 + ldst);                                   \
    }                                                                   \
  } while (0)

  // ---- reader: frag row = base + (lane&15); kgroup = lane>>4 covers slots
  // {2k, 2k+1}, each XOR'd by row&7 == lane&7.
  const int rA = (wr * 64 + (lane & 15)) * 128;
  const int rB = 16384 + (wc * 64 + (lane & 15)) * 128;
  const int k2 = (lane >> 4) * 2;
  const int sw = lane & 7;
  const int o0 = (k2 ^ sw) * 16;
  const int o1 = ((k2 + 1) ^ sw) * 16;

  f32x4 acc[4][4];
#pragma unroll
  for (int i = 0; i < 4; ++i)
#pragma unroll
    for (int j = 0; j < 4; ++j) acc[i][j] = (f32x4){0.f, 0.f, 0.f, 0.f};

  for (int t = 0; t < 4; ++t) {
    STAGE(t);
    __syncthreads();  // drains vmcnt(0): tile resident

    i32x8 a[4], b[4];
#pragma unroll
    for (int mi = 0; mi < 4; ++mi) {
      const i32x4 lo = *(const i32x4*)(lds + rA + mi * 2048 + o0);
      const i32x4 hi = *(const i32x4*)(lds + rA + mi * 2048 + o1);
      a[mi] = (i32x8){lo[0], lo[1], lo[2], lo[3], hi[0], hi[1], hi[2], hi[3]};
    }
#pragma unroll
    for (int ni = 0; ni < 4; ++ni) {
      const i32x4 lo = *(const i32x4*)(lds + rB + ni * 2048 + o0);
      const i32x4 hi = *(const i32x4*)(lds + rB + ni * 2048 + o1);
      b[ni] = (i32x8){lo[0], lo[1], lo[2], lo[3], hi[0], hi[1], hi[2], hi[3]};
    }
#pragma unroll
    for (int mi = 0; mi < 4; ++mi)
#pragma unroll
      for (int ni = 0; ni < 4; ++ni)
        acc[mi][ni] = __builtin_amdgcn_mfma_scale_f32_16x16x128_f8f6f4(
            a[mi], b[ni], acc[mi][ni], 0, 0,  // cbsz=0 (fp8), blgp=0 (fp8)
            0, 0x7F7F7F7F,                    // scale A opsel, E8M0 1.0
            0, 0x7F7F7F7F);                   // scale B opsel, E8M0 1.0
    __syncthreads();  // compute done before next stage overwrites
  }

  // ---- fused relu + (==1 -> 0) + row sums (r2-proven) -------------------
  // C/D layout (shape-determined): col = lane&15, row(frag) = (lane>>4)*4+reg
  float rs[4][4];
#pragma unroll
  for (int mi = 0; mi < 4; ++mi)
#pragma unroll
    for (int r = 0; r < 4; ++r) rs[mi][r] = 0.0f;
#pragma unroll
  for (int mi = 0; mi < 4; ++mi)
#pragma unroll
    for (int ni = 0; ni < 4; ++ni)
#pragma unroll
      for (int r = 0; r < 4; ++r) {
        float v = acc[mi][ni][r];
        v = v > 0.0f ? v : 0.0f;
        v = (v == 1.0f) ? 0.0f : v;
        rs[mi][r] += v;
      }
#pragma unroll
  for (int mi = 0; mi < 4; ++mi)
#pragma unroll
    for (int r = 0; r < 4; ++r) {
      float s = rs[mi][r];
      s += __shfl_xor(s, 1);
      s += __shfl_xor(s, 2);
      s += __shfl_xor(s, 4);
      s += __shfl_xor(s, 8);
      if ((lane & 15) == 0)
        atomicAdd(&S_all[m0 + wr * 64 + mi * 16 + (lane >> 4) * 4 + r], s);
    }
}

// ---------------------------------------------------------------------------
// Finalize: rank + global sum. Single block, 1024 threads.
// ---------------------------------------------------------------------------
__global__ __launch_bounds__(1024) void grl_final(
    const float* __restrict__ S_all, const float* __restrict__ diagm,
    const float* __restrict__ pos, const float* __restrict__ mask,
    float* __restrict__ out) {
  __shared__ float red[16];
  const int lane = threadIdx.x & 63;
  const int wv = threadIdx.x >> 6;
  float s = 0.0f;
  for (int r = threadIdx.x; r < M_TOT; r += 1024) {
    const float neg = (S_all[r] - diagm[r]) / 255.0f;  // 255 + 1e-8 == 255.0f
    float rank = neg - pos[r] + 0.2f;
    rank = rank > 0.0f ? rank : 0.0f;
    s += rank * mask[r];
  }
#pragma unroll
  for (int off = 1; off < 64; off <<= 1) s += __shfl_xor(s, off);
  if (lane == 0) red[wv] = s;
  __syncthreads();
  if (threadIdx.x == 0) {
    float t = 0.0f;
#pragma unroll
    for (int i = 0; i < 16; ++i) t += red[i];
    out[0] = t / 256.0f;  // BETA * sum / B
  }
}

// ---------------------------------------------------------------------------
extern "C" void kernel_launch(void* const* d_in, const int* in_sizes, int n_in,
                              void* d_out, int out_size, void* d_ws, size_t ws_size,
                              hipStream_t stream) {
  const float* face = (const float*)d_in[0];
  const float* ner = (const float*)d_in[1];

  unsigned char* face8 = (unsigned char*)d_ws;                       // 4 MB
  unsigned char* ner8 = face8 + (size_t)M_TOT * DIM_D;               // 2 MB
  float* S_all = (float*)(ner8 + (size_t)N_TOT * DIM_D);
  float* diagm = S_all + M_TOT;
  float* pos = diagm + M_TOT;
  float* mask = pos + M_TOT;

  hipMemsetAsync(S_all, 0, M_TOT * sizeof(float), stream);
  cvt_fp8<<<(M_TOT + N_TOT) / 4, 256, 0, stream>>>(face, ner, face8, ner8,
                                                   mask);
  grl_diag<<<M_TOT / 4, 256, 0, stream>>>(face, ner, pos, diagm);
  grl_gemm_fp8<<<dim3(M_TOT / 128, N_TOT / 128), 256, 0, stream>>>(
      face8, ner8, S_all);
  grl_final<<<1, 1024, 0, stream>>>(S_all, diagm, pos, mask, (float*)d_out);
}

// Round 12
// 72.545 us; speedup vs baseline: 1.8377x; 1.8377x over previous
//
#include <hip/hip_runtime.h>

// B=256, F=32, N=16, D=512
//   sims[b,f,c,n] = relu(face[b,f]·ner[c,n])      (8192 x 4096 NT GEMM, K=512)
//   S_all[b,f]    = sum_{c,n} masked(sims)        (masked: ==1.0 -> 0)
//   pos[b,f]      = sum_n sims[b,f,b,n]           (unmasked diagonal)
//   diag_m[b,f]   = sum_n masked(sims[b,f,b,n])
//   loss = sum(relu((S_all-diag_m)/255 - pos + 0.2) * face_mask) / 256
//
// Round 12: maximize COMPUTE PER SYNC. 256x256 tile, BK=64, 8 waves
// (wave-tile 128x64), double-buffered 128 KiB LDS. Per K-tile (8 total):
// one contiguous 64-MFMA compute phase (~2500 cyc/SIMD), then ONE
// vmcnt(0)-with-full-iteration-lead + ONE s_barrier + stage of tile t+2.
// (All prior rounds chopped compute into 300-600 cyc slices between syncs
// with ~500-900 cyc stall each -> ~20% MfmaUtil; r1-fp32 proved 72% busy
// with 4000-cyc phases in the same loop shape.) bf16 end-to-end (absmax 0.0
// proven); 8-slot XOR swizzle (slot ^= row&7), pre-swizzled source (rule 21).

#define DIM_D 512
#define M_TOT 8192
#define N_TOT 4096

typedef __attribute__((ext_vector_type(8))) short short8v;
typedef __attribute__((ext_vector_type(4))) float f32x4;

__device__ __forceinline__ unsigned short f2bf(float f) {
  unsigned int u = __builtin_bit_cast(unsigned int, f);
  u += 0x7fffu + ((u >> 16) & 1u);
  return (unsigned short)(u >> 16);
}

// ---------------------------------------------------------------------------
// Merged cvt: face+ner fp32 -> bf16, plus face_mask (fp32 row-sum != 0).
// ---------------------------------------------------------------------------
__global__ __launch_bounds__(256) void cvt_all(
    const float* __restrict__ face, const float* __restrict__ ner,
    unsigned short* __restrict__ face_bf, unsigned short* __restrict__ ner_bf,
    float* __restrict__ mask) {
  const int gw = blockIdx.x * 4 + (threadIdx.x >> 6);
  const int lane = threadIdx.x & 63;
  const bool isFace = gw < M_TOT;
  const int row = isFace ? gw : gw - M_TOT;
  const float* src = (isFace ? face : ner) + (size_t)row * DIM_D;
  unsigned short* dst = (isFace ? face_bf : ner_bf) + (size_t)row * DIM_D;

  const float4 f0 = ((const float4*)src)[lane * 2];
  const float4 f1 = ((const float4*)src)[lane * 2 + 1];
  short8v o;
  o[0] = (short)f2bf(f0.x); o[1] = (short)f2bf(f0.y);
  o[2] = (short)f2bf(f0.z); o[3] = (short)f2bf(f0.w);
  o[4] = (short)f2bf(f1.x); o[5] = (short)f2bf(f1.y);
  o[6] = (short)f2bf(f1.z); o[7] = (short)f2bf(f1.w);
  *(short8v*)(dst + lane * 8) = o;

  if (isFace) {
    float fs = f0.x + f0.y + f0.z + f0.w + f1.x + f1.y + f1.z + f1.w;
#pragma unroll
    for (int off = 1; off < 64; off <<= 1) fs += __shfl_xor(fs, off);
    if (lane == 0) mask[row] = (fs != 0.0f) ? 1.0f : 0.0f;
  }
}

// ---------------------------------------------------------------------------
// 256x256 bf16 GEMM, BK=64, 8 waves (2M x 4N), wave-tile 128x64.
// LDS buffer b (b = T&1) at b*32768 shorts: A rows [0,16384), B [16384,32768);
// row r at r*64 shorts (128 B = 8 x 16B slots). Slot s of row r holds global
// k-slot s ^ (r&7). Staged with pre-swizzled global source, linear LDS dst.
// ---------------------------------------------------------------------------
#define MFMA(A_, B_, C_) __builtin_amdgcn_mfma_f32_16x16x32_bf16(A_, B_, C_, 0, 0, 0)

#define GLDS(SRC, DSTOFF)                                                     \
  __builtin_amdgcn_global_load_lds(                                           \
      (const __attribute__((address_space(1))) void*)(SRC),                   \
      (__attribute__((address_space(3))) void*)(lds + (DSTOFF)), 16, 0, 0)

__global__ __launch_bounds__(512, 1) void grl_gemm256(
    const unsigned short* __restrict__ A, const unsigned short* __restrict__ Bn,
    float* __restrict__ S_all, float* __restrict__ pos,
    float* __restrict__ diagm) {
  extern __shared__ unsigned short lds[];  // 2 x 32768 shorts = 128 KiB

  const int tid = threadIdx.x;
  const int lane = tid & 63;
  const int wid = tid >> 6;
  const int wr = wid >> 2;     // 0..1 (M half)
  const int wc = wid & 3;      // 0..3 (N quarter)
  const int by = blockIdx.x;   // 0..15 (N)
  const int bx = blockIdx.y;   // 0..31 (M)
  const int m0 = bx * 256;
  const int n0 = by * 256;

  // ---- stager: instr i covers rows [i*64, i*64+64) ----------------------
  // lane -> row = i*64 + wid*8 + (lane>>3), slot = lane&7;
  // source k-slot g = (lane&7) ^ (row&7) = (lane&7) ^ (lane>>3).
  const int g = (lane & 7) ^ (lane >> 3);
  const unsigned short* gA =
      A + (size_t)(m0 + wid * 8 + (lane >> 3)) * DIM_D + g * 8;
  const unsigned short* gB =
      Bn + (size_t)(n0 + wid * 8 + (lane >> 3)) * DIM_D + g * 8;
  const int wdst = wid * 512;  // wave-uniform; HW adds lane*16B

#define STAGE(T)                                                          \
  do {                                                                    \
    const int bb_ = ((T)&1) * 32768;                                      \
    _Pragma("unroll") for (int i_ = 0; i_ < 4; ++i_) {                    \
      GLDS(gA + (T) * 64 + (size_t)i_ * 64 * DIM_D, bb_ + i_ * 4096 + wdst); \
      GLDS(gB + (T) * 64 + (size_t)i_ * 64 * DIM_D,                       \
           bb_ + 16384 + i_ * 4096 + wdst);                               \
    }                                                                     \
  } while (0)

  // ---- reader: frag row = base + (lane&15); global k-slot ks*4+(lane>>4),
  // LDS slot = that ^ (row&7), and row&7 == lane&7 for 16-aligned bases.
  const int sw = lane & 7;
  const int kq = lane >> 4;
  const int s0 = (kq ^ sw) * 8;        // ks = 0 (shorts)
  const int s1 = ((4 + kq) ^ sw) * 8;  // ks = 1
  const int rA = (wr * 128 + (lane & 15)) * 64;           // + mi*1024
  const int rB = 16384 + (wc * 64 + (lane & 15)) * 64;    // + ni*1024

  f32x4 acc[8][4];
#pragma unroll
  for (int i = 0; i < 8; ++i)
#pragma unroll
    for (int j = 0; j < 4; ++j) acc[i][j] = (f32x4){0.f, 0.f, 0.f, 0.f};

#define MFMA16(G)                                          \
  acc[(G)*4 + 0][0] = MFMA(a0, b0, acc[(G)*4 + 0][0]);     \
  acc[(G)*4 + 0][1] = MFMA(a0, b1, acc[(G)*4 + 0][1]);     \
  acc[(G)*4 + 0][2] = MFMA(a0, b2, acc[(G)*4 + 0][2]);     \
  acc[(G)*4 + 0][3] = MFMA(a0, b3, acc[(G)*4 + 0][3]);     \
  acc[(G)*4 + 1][0] = MFMA(a1, b0, acc[(G)*4 + 1][0]);     \
  acc[(G)*4 + 1][1] = MFMA(a1, b1, acc[(G)*4 + 1][1]);     \
  acc[(G)*4 + 1][2] = MFMA(a1, b2, acc[(G)*4 + 1][2]);     \
  acc[(G)*4 + 1][3] = MFMA(a1, b3, acc[(G)*4 + 1][3]);     \
  acc[(G)*4 + 2][0] = MFMA(a2, b0, acc[(G)*4 + 2][0]);     \
  acc[(G)*4 + 2][1] = MFMA(a2, b1, acc[(G)*4 + 2][1]);     \
  acc[(G)*4 + 2][2] = MFMA(a2, b2, acc[(G)*4 + 2][2]);     \
  acc[(G)*4 + 2][3] = MFMA(a2, b3, acc[(G)*4 + 2][3]);     \
  acc[(G)*4 + 3][0] = MFMA(a3, b0, acc[(G)*4 + 3][0]);     \
  acc[(G)*4 + 3][1] = MFMA(a3, b1, acc[(G)*4 + 3][1]);     \
  acc[(G)*4 + 3][2] = MFMA(a3, b2, acc[(G)*4 + 3][2]);     \
  acc[(G)*4 + 3][3] = MFMA(a3, b3, acc[(G)*4 + 3][3]);

// One K-tile: 24 ds_read_b128 + 64 MFMA, NO internal barriers (compiler
// schedules lgkmcnt); ks-major grouping so B frags are read once per ks.
#define COMPUTE(T)                                                        \
  do {                                                                    \
    const unsigned short* Lb = lds + ((T)&1) * 32768;                     \
    short8v a0, a1, a2, a3, b0, b1, b2, b3;                               \
    b0 = *(const short8v*)(Lb + rB + 0 * 1024 + s0);                      \
    b1 = *(const short8v*)(Lb + rB + 1 * 1024 + s0);                      \
    b2 = *(const short8v*)(Lb + rB + 2 * 1024 + s0);                      \
    b3 = *(const short8v*)(Lb + rB + 3 * 1024 + s0);                      \
    a0 = *(const short8v*)(Lb + rA + 0 * 1024 + s0);                      \
    a1 = *(const short8v*)(Lb + rA + 1 * 1024 + s0);                      \
    a2 = *(const short8v*)(Lb + rA + 2 * 1024 + s0);                      \
    a3 = *(const short8v*)(Lb + rA + 3 * 1024 + s0);                      \
    MFMA16(0)                                                             \
    a0 = *(const short8v*)(Lb + rA + 4 * 1024 + s0);                      \
    a1 = *(const short8v*)(Lb + rA + 5 * 1024 + s0);                      \
    a2 = *(const short8v*)(Lb + rA + 6 * 1024 + s0);                      \
    a3 = *(const short8v*)(Lb + rA + 7 * 1024 + s0);                      \
    MFMA16(1)                                                             \
    b0 = *(const short8v*)(Lb + rB + 0 * 1024 + s1);                      \
    b1 = *(const short8v*)(Lb + rB + 1 * 1024 + s1);                      \
    b2 = *(const short8v*)(Lb + rB + 2 * 1024 + s1);                      \
    b3 = *(const short8v*)(Lb + rB + 3 * 1024 + s1);                      \
    a0 = *(const short8v*)(Lb + rA + 0 * 1024 + s1);                      \
    a1 = *(const short8v*)(Lb + rA + 1 * 1024 + s1);                      \
    a2 = *(const short8v*)(Lb + rA + 2 * 1024 + s1);                      \
    a3 = *(const short8v*)(Lb + rA + 3 * 1024 + s1);                      \
    MFMA16(0)                                                             \
    a0 = *(const short8v*)(Lb + rA + 4 * 1024 + s1);                      \
    a1 = *(const short8v*)(Lb + rA + 5 * 1024 + s1);                      \
    a2 = *(const short8v*)(Lb + rA + 6 * 1024 + s1);                      \
    a3 = *(const short8v*)(Lb + rA + 7 * 1024 + s1);                      \
    MFMA16(1)                                                             \
  } while (0)

  // ---- prologue: tiles 0,1 in flight; wait tile 0 (counted) -------------
  STAGE(0);
  STAGE(1);
  asm volatile("s_waitcnt vmcnt(8)" ::: "memory");
  __builtin_amdgcn_s_barrier();

  // ---- main loop: one barrier + one old-load vmcnt(0) per K-tile --------
  for (int t = 0; t < 6; ++t) {
    COMPUTE(t);
    asm volatile("s_waitcnt vmcnt(0)" ::: "memory");  // tile t+1 (1-iter lead)
    __builtin_amdgcn_s_barrier();
    STAGE(t + 2);  // into buf[t&1], just freed by all waves
  }
  COMPUTE(6);
  asm volatile("s_waitcnt vmcnt(0)" ::: "memory");    // tile 7 landed
  __builtin_amdgcn_s_barrier();
  COMPUTE(7);

  // ---- fused relu + (==1 -> 0) + per-thread row sums --------------------
  // C/D layout: col = lane&15 (n), row(frag) = (lane>>4)*4 + reg
  float rs[8][4];
#pragma unroll
  for (int mi = 0; mi < 8; ++mi)
#pragma unroll
    for (int r = 0; r < 4; ++r) rs[mi][r] = 0.0f;
#pragma unroll
  for (int mi = 0; mi < 8; ++mi)
#pragma unroll
    for (int ni = 0; ni < 4; ++ni)
#pragma unroll
      for (int r = 0; r < 4; ++r) {
        float v = acc[mi][ni][r];
        v = v > 0.0f ? v : 0.0f;
        v = (v == 1.0f) ? 0.0f : v;
        rs[mi][r] += v;
      }
#pragma unroll
  for (int mi = 0; mi < 8; ++mi)
#pragma unroll
    for (int r = 0; r < 4; ++r) {
      float s = rs[mi][r];
      s += __shfl_xor(s, 1);
      s += __shfl_xor(s, 2);
      s += __shfl_xor(s, 4);
      s += __shfl_xor(s, 8);
      if ((lane & 15) == 0)
        atomicAdd(&S_all[m0 + wr * 128 + mi * 16 + (lane >> 4) * 4 + r], s);
    }

  // ---- fused diagonal (blocks with by == bx>>1 only) --------------------
  if (by == (bx >> 1)) {
#pragma unroll
    for (int mi = 0; mi < 8; ++mi) {
      const int R0 = m0 + wr * 128 + mi * 16;  // rows R0..R0+15 share b_
      const int tc = ((R0 >> 5) << 4) - n0;    // diag col offset in tile
      if ((tc >> 6) == wc) {
        const int dn = (tc >> 4) & 3;
#pragma unroll
        for (int ni = 0; ni < 4; ++ni)
          if (ni == dn) {
#pragma unroll
            for (int r = 0; r < 4; ++r) {
              float v = acc[mi][ni][r];
              v = v > 0.0f ? v : 0.0f;
              float vm = (v == 1.0f) ? 0.0f : v;
              float ps = v, ds = vm;
              ps += __shfl_xor(ps, 1); ds += __shfl_xor(ds, 1);
              ps += __shfl_xor(ps, 2); ds += __shfl_xor(ds, 2);
              ps += __shfl_xor(ps, 4); ds += __shfl_xor(ds, 4);
              ps += __shfl_xor(ps, 8); ds += __shfl_xor(ds, 8);
              if ((lane & 15) == 0) {
                const int R = R0 + (lane >> 4) * 4 + r;
                pos[R] = ps;
                diagm[R] = ds;
              }
            }
          }
      }
    }
  }
}

// ---------------------------------------------------------------------------
// Finalize: rank + global sum. Single block, 1024 threads.
// ---------------------------------------------------------------------------
__global__ __launch_bounds__(1024) void grl_final(
    const float* __restrict__ S_all, const float* __restrict__ diagm,
    const float* __restrict__ pos, const float* __restrict__ mask,
    float* __restrict__ out) {
  __shared__ float red[16];
  const int lane = threadIdx.x & 63;
  const int wv = threadIdx.x >> 6;
  float s = 0.0f;
  for (int r = threadIdx.x; r < M_TOT; r += 1024) {
    const float neg = (S_all[r] - diagm[r]) / 255.0f;  // 255 + 1e-8 == 255.0f
    float rank = neg - pos[r] + 0.2f;
    rank = rank > 0.0f ? rank : 0.0f;
    s += rank * mask[r];
  }
#pragma unroll
  for (int off = 1; off < 64; off <<= 1) s += __shfl_xor(s, off);
  if (lane == 0) red[wv] = s;
  __syncthreads();
  if (threadIdx.x == 0) {
    float t = 0.0f;
#pragma unroll
    for (int i = 0; i < 16; ++i) t += red[i];
    out[0] = t / 256.0f;  // BETA * sum / B
  }
}

// ---------------------------------------------------------------------------
extern "C" void kernel_launch(void* const* d_in, const int* in_sizes, int n_in,
                              void* d_out, int out_size, void* d_ws, size_t ws_size,
                              hipStream_t stream) {
  const float* face = (const float*)d_in[0];
  const float* ner = (const float*)d_in[1];

  unsigned short* face_bf = (unsigned short*)d_ws;
  unsigned short* ner_bf = face_bf + (size_t)M_TOT * DIM_D;
  float* S_all = (float*)(ner_bf + (size_t)N_TOT * DIM_D);
  float* diagm = S_all + M_TOT;
  float* pos = diagm + M_TOT;
  float* mask = pos + M_TOT;

  hipFuncSetAttribute((const void*)grl_gemm256,
                      hipFuncAttributeMaxDynamicSharedMemorySize, 131072);

  hipMemsetAsync(S_all, 0, M_TOT * sizeof(float), stream);
  cvt_all<<<(M_TOT + N_TOT) / 4, 256, 0, stream>>>(face, ner, face_bf, ner_bf,
                                                   mask);
  grl_gemm256<<<dim3(N_TOT / 256, M_TOT / 256), 512, 131072, stream>>>(
      face_bf, ner_bf, S_all, pos, diagm);
  grl_final<<<1, 1024, 0, stream>>>(S_all, diagm, pos, mask, (float*)d_out);
}